// Round 11
// baseline (163.060 us; speedup 1.0000x reference)
//
#include <hip/hip_runtime.h>
#include <math.h>

// Problem constants
#define BATCH   8
#define SEQLEN  2048
#define DMODEL  1024
#define KFREQ   513
#define NSPEC   1024       // pair layout: col 2j=Re_j, col 2j+1=Im_j (j=1..511); col1 = Re_512
#define NPAIR   512
#define BT_ROWS (BATCH*SEQLEN)   // 16384
#define NC      32
#define TC      64

static_assert(NC * TC == SEQLEN, "chunking must cover SEQLEN");

typedef __attribute__((ext_vector_type(4))) float f32x4;
typedef __attribute__((ext_vector_type(8))) short bf16x8;
typedef unsigned short ushort_t;
typedef unsigned int uint_t;

__device__ __forceinline__ ushort_t f2bf(float f) {
    union { float f; unsigned u; } v; v.f = f;
    unsigned r = v.u + 0x7FFFu + ((v.u >> 16) & 1u);   // RNE
    return (ushort_t)(r >> 16);
}
__device__ __forceinline__ float bf2f(ushort_t b) {
    union { unsigned u; float f; } v; v.u = ((unsigned)b) << 16;
    return v.f;
}

__device__ __forceinline__ void async_cp16(const void* g, void* l) {
    __builtin_amdgcn_global_load_lds(
        (const __attribute__((address_space(1))) void*)g,
        (__attribute__((address_space(3))) void*)l, 16, 0, 0);
}

#define BAR()   __builtin_amdgcn_s_barrier()
#define PRIO1() __builtin_amdgcn_s_setprio(1)
#define PRIO0() __builtin_amdgcn_s_setprio(0)
#define LGKM0() asm volatile("s_waitcnt lgkmcnt(0)" ::: "memory")
#define LGKM8() asm volatile("s_waitcnt lgkmcnt(8)" ::: "memory")
#define VM6()   asm volatile("s_waitcnt vmcnt(6)" ::: "memory")
#define VM0()   asm volatile("s_waitcnt vmcnt(0)" ::: "memory")

#define SINSTEP 0.00613592315154256491887f   // 2*pi/1024

// ---------------------------------------------------------------------------
// prep_all — one dispatch:
//  bid 0                    : lambda (pair layout) + dflag
//  bid 1 .. 2*NB_T          : trig matrices T1b (mode0) / T2b (mode1)
//  next NB_TR               : Bw transpose-convert
//  next NB_CW               : Cw -> bf16
// ---------------------------------------------------------------------------
#define NB_T  (NSPEC * DMODEL / 8 / 256)     // 512 per mode
#define NB_TR 256
#define NB_CW (DMODEL * DMODEL / 8 / 256)    // 512
#define NB_U  (BT_ROWS * DMODEL / 8 / 256)   // 8192

__global__ __launch_bounds__(256) void prep_all(const float* __restrict__ ap,
                                                float* __restrict__ lam,
                                                const float* __restrict__ Dv,
                                                int* __restrict__ dflag,
                                                const float* __restrict__ Cw,
                                                ushort_t* __restrict__ Cwb,
                                                const float* __restrict__ Bw,
                                                ushort_t* __restrict__ BwTb,
                                                ushort_t* __restrict__ T1b,
                                                ushort_t* __restrict__ T2b) {
    const int bid = blockIdx.x;
    if (bid == 0) {
        // --- lambda + dflag (256-thread variant) ---
        __shared__ float stab[1024];
        __shared__ int anyd;
        if (threadIdx.x == 0) anyd = 0;
        for (int j = threadIdx.x; j < 1024; j += 256)
            stab[j] = sinf((float)j * SINSTEP);
        __syncthreads();
        for (int q = threadIdx.x; q < 1024; q += 256)
            if (Dv[q] != 0.0f) anyd = 1;            // benign race
        for (int f = threadIdx.x; f < KFREQ; f += 256) {
            float om = 0.0f;
            for (int j = 1; j <= 511; ++j)
                om = fmaf(ap[j - 1], stab[(j * f) & 1023], om);
            om *= -2.0f;
            const float w2 = om * om;
            const float den = 1.0f + w2;
            const float re = (1.0f - w2) / den;
            const float im = -2.0f * om / den;
            if (f == 0)        lam[0] = re;
            else if (f == 512) lam[1] = re;
            else { lam[2 * f] = re; lam[2 * f + 1] = im; }
        }
        __syncthreads();
        if (threadIdx.x == 0) *dflag = anyd;
    } else if (bid < 1 + 2 * NB_T) {
        // --- trig matrix, pair-layout rows ---
        __shared__ float stab[1024];
        for (int j = threadIdx.x; j < 1024; j += 256)
            stab[j] = sinf((float)j * SINSTEP);
        __syncthreads();
        const int t = bid - 1;
        const int mode = t >= NB_T;
        ushort_t* T = mode ? T2b : T1b;
        const int i = (t - mode * NB_T) * 256 + threadIdx.x;
        const int row = i >> 7;
        const int nb  = (i & 127) << 3;
        const int kf  = (row == 1) ? 512 : (row >> 1);
        const bool sb = (row & 1) && (row != 1);        // sine basis?
        float scale = 1.0f;
        if (mode) scale = ((row < 2) ? 1.0f : 2.0f) / 1024.0f;
        ushort_t o[8];
        int m = (kf * nb) & 1023;
#pragma unroll
        for (int j = 0; j < 8; ++j) {
            const float v = sb ? -stab[m] : stab[(m + 256) & 1023];
            o[j] = f2bf(v * scale);
            m = (m + kf) & 1023;
        }
        reinterpret_cast<bf16x8*>(T)[i] = *reinterpret_cast<bf16x8*>(o);
    } else if (bid < 1 + 2 * NB_T + NB_TR) {
        // --- Bw transpose-convert ---
        __shared__ float tile[64][65];
        const int b2 = bid - (1 + 2 * NB_T);
        const int bx = (b2 & 15) * 64;
        const int by = (b2 >> 4) * 64;
        const int lx = threadIdx.x & 63;
        const int ly = threadIdx.x >> 6;
#pragma unroll
        for (int i = 0; i < 16; ++i) {
            const int r = ly + i * 4;
            tile[r][lx] = Bw[(size_t)(by + r) * DMODEL + bx + lx];
        }
        __syncthreads();
#pragma unroll
        for (int i = 0; i < 16; ++i) {
            const int r = ly + i * 4;
            BwTb[(size_t)(bx + r) * DMODEL + by + lx] = f2bf(tile[lx][r]);
        }
    } else {
        // --- Cw -> bf16 ---
        const int b3 = bid - (1 + 2 * NB_T + NB_TR);
        const int i = b3 * 256 + threadIdx.x;
        const float4 a = reinterpret_cast<const float4*>(Cw)[2 * i];
        const float4 b = reinterpret_cast<const float4*>(Cw)[2 * i + 1];
        ushort_t o[8] = {f2bf(a.x), f2bf(a.y), f2bf(a.z), f2bf(a.w),
                         f2bf(b.x), f2bf(b.y), f2bf(b.z), f2bf(b.w)};
        reinterpret_cast<bf16x8*>(Cwb)[i] = *reinterpret_cast<bf16x8*>(o);
    }
}

// ---------------------------------------------------------------------------
// conv_and_gemm128 — one dispatch: first 128 blocks run the two 128x128 BK=32
// weight GEMMs (compute-bound, would leave GPU half-idle alone); remaining
// 8192 blocks convert u -> bf16 (BW-bound) and fill the idle CUs.
// ---------------------------------------------------------------------------
__global__ __launch_bounds__(256) void conv_and_gemm128(
        const float* __restrict__ u, ushort_t* __restrict__ ub,
        const ushort_t* __restrict__ A0, const ushort_t* __restrict__ B0,
        ushort_t* __restrict__ C0,
        const ushort_t* __restrict__ A1, const ushort_t* __restrict__ B1,
        ushort_t* __restrict__ C1) {
    const int bid = blockIdx.x;
    if (bid >= 128) {
        // --- u -> bf16 ---
        const int i = (bid - 128) * 256 + threadIdx.x;
        const float4 a = reinterpret_cast<const float4*>(u)[2 * i];
        const float4 b = reinterpret_cast<const float4*>(u)[2 * i + 1];
        ushort_t o[8] = {f2bf(a.x), f2bf(a.y), f2bf(a.z), f2bf(a.w),
                         f2bf(b.x), f2bf(b.y), f2bf(b.z), f2bf(b.w)};
        reinterpret_cast<bf16x8*>(ub)[i] = *reinterpret_cast<bf16x8*>(o);
        return;
    }
    // --- 128x128 BK=32 GEMM, z = bid>>6 selects operand triple ---
    const int K = 1024, N = 1024;
    const int z = bid >> 6;
    const ushort_t* A = z ? A1 : A0;
    const ushort_t* B = z ? B1 : B0;
    ushort_t*       C = z ? C1 : C0;
    const int g = bid & 63;
    const int m0 = (g >> 3) * 128;
    const int n0 = (g & 7) * 128;
    __shared__ ushort_t As[128 * 32];
    __shared__ ushort_t Bs[128 * 32];
    const int tid  = threadIdx.x;
    const int lane = tid & 63;
    const int w    = tid >> 6;
    const int wr = (w >> 1) * 64;
    const int wc = (w & 1) * 64;

    f32x4 acc[4][4] = {};

    const int pos  = w * 512 + lane * 8;
    const int srow = pos >> 5;
    const int scol = pos & 31;
    const int lr = lane & 15;
    const int lk = (lane >> 4) * 8;

    for (int k0 = 0; k0 < K; k0 += 32) {
        __syncthreads();
        async_cp16(A + (size_t)(m0 + srow)      * K + k0 + scol, As + w * 512);
        async_cp16(A + (size_t)(m0 + srow + 64) * K + k0 + scol, As + 2048 + w * 512);
        async_cp16(B + (size_t)(n0 + srow)      * K + k0 + scol, Bs + w * 512);
        async_cp16(B + (size_t)(n0 + srow + 64) * K + k0 + scol, Bs + 2048 + w * 512);
        __syncthreads();

        bf16x8 fa[4], fb[4];
#pragma unroll
        for (int mi = 0; mi < 4; ++mi)
            fa[mi] = *reinterpret_cast<const bf16x8*>(&As[(wr + mi * 16 + lr) * 32 + lk]);
#pragma unroll
        for (int ni = 0; ni < 4; ++ni)
            fb[ni] = *reinterpret_cast<const bf16x8*>(&Bs[(wc + ni * 16 + lr) * 32 + lk]);
#pragma unroll
        for (int mi = 0; mi < 4; ++mi)
#pragma unroll
            for (int ni = 0; ni < 4; ++ni)
                acc[mi][ni] = __builtin_amdgcn_mfma_f32_16x16x32_bf16(
                    fa[mi], fb[ni], acc[mi][ni], 0, 0, 0);
    }

    const int rbase = (lane >> 4) * 4;
#pragma unroll
    for (int mi = 0; mi < 4; ++mi)
#pragma unroll
        for (int ni = 0; ni < 4; ++ni) {
            const int col = n0 + wc + ni * 16 + lr;
#pragma unroll
            for (int j = 0; j < 4; ++j) {
                const int row = m0 + wr + mi * 16 + rbase + j;
                C[(size_t)row * N + col] = f2bf(acc[mi][ni][j]);
            }
        }
}

// ---------------------------------------------------------------------------
// Generalized pair recurrence coefficients (j=0 packs DC + Nyquist reals).
// ---------------------------------------------------------------------------
__device__ __forceinline__ void pair_coef(const float* lam, int j,
                                          float& lr, float& lr2, float& cr) {
    const float a = lam[2 * j];
    const float b = lam[2 * j + 1];
    if (j == 0) { lr = a; lr2 = b; cr = 0.0f; }
    else        { lr = a; lr2 = a; cr = b; }
}

// ---------------------------------------------------------------------------
// 256x256 8-wave bf16 MFMA GEMM — m201-style 8-phase schedule (round-8 proven;
// epilogue switched by SCANEPI). Byte-identical to round 10.
// ---------------------------------------------------------------------------
template <int MH, int NH>
__device__ __forceinline__ void quad_mfma(f32x4 (&acc)[2][2][4][2],
                                          const bf16x8 (&fa)[4][2],
                                          const bf16x8 (&fb)[2][2]) {
#pragma unroll
    for (int mi = 0; mi < 4; ++mi)
#pragma unroll
        for (int ni = 0; ni < 2; ++ni) {
            acc[MH][NH][mi][ni] = __builtin_amdgcn_mfma_f32_16x16x32_bf16(
                fa[mi][0], fb[ni][0], acc[MH][NH][mi][ni], 0, 0, 0);
            acc[MH][NH][mi][ni] = __builtin_amdgcn_mfma_f32_16x16x32_bf16(
                fa[mi][1], fb[ni][1], acc[MH][NH][mi][ni], 0, 0, 0);
        }
}

__device__ __forceinline__ void ld_fa(bf16x8 (&fa)[4][2], const ushort_t* hb,
                                      int wm, int lr, int c0, int c1) {
#pragma unroll
    for (int mi = 0; mi < 4; ++mi) {
        const ushort_t* p = hb + (wm * 64 + mi * 16 + lr) * 64;
        fa[mi][0] = *reinterpret_cast<const bf16x8*>(p + c0);
        fa[mi][1] = *reinterpret_cast<const bf16x8*>(p + c1);
    }
}
__device__ __forceinline__ void ld_fb(bf16x8 (&fb)[2][2], const ushort_t* hb,
                                      int wn, int lr, int c0, int c1) {
#pragma unroll
    for (int ni = 0; ni < 2; ++ni) {
        const ushort_t* p = hb + (wn * 32 + ni * 16 + lr) * 64;
        fb[ni][0] = *reinterpret_cast<const bf16x8*>(p + c0);
        fb[ni][1] = *reinterpret_cast<const bf16x8*>(p + c1);
    }
}

#define HS_STRIDE 260

template <bool SCANEPI>
__global__ __launch_bounds__(512, 2) void gemm256(const ushort_t* __restrict__ A,
                                                  const ushort_t* __restrict__ B,
                                                  void* __restrict__ Cv,
                                                  int M, int K,
                                                  const float* __restrict__ uu,
                                                  const float* __restrict__ Dv,
                                                  const int* __restrict__ dflag,
                                                  const float* __restrict__ lam,
                                                  float2* __restrict__ G) {
    __shared__ ushort_t smem[66560];   // As/Bs (65536) aliased with Hs (66560B*2=133120 B)
    const int tid  = threadIdx.x;
    const int lane = tid & 63;
    const int w    = tid >> 6;      // 0..7
    const int wm   = w >> 2;        // 0..1
    const int wn   = w & 3;         // 0..3
    const int m0 = blockIdx.x * 256;
    const int n0 = blockIdx.y * 256;
    const int lr = lane & 15;
    const int lk = (lane >> 4) * 8;
    const int xv = (lr & 7) << 3;
    const int c0 = lk ^ xv;
    const int c1 = (32 + lk) ^ xv;

    const int rA = tid >> 3;
    const int cS = ((tid & 7) << 3) ^ ((rA & 7) << 3);
    const int ldsOff = w << 9;

    auto ApH = [&](int buf, int half) { return smem + (buf * 2 + half) * 8192; };
    auto BpH = [&](int buf, int half) { return smem + 32768 + (buf * 2 + half) * 8192; };

    f32x4 acc[2][2][4][2] = {};
    bf16x8 fa[4][2], fbl[2][2], fbh[2][2];

    auto stA = [&](int buf, int half, int k) {
#pragma unroll
        for (int li = 0; li < 2; ++li)
            async_cp16(A + (size_t)(m0 + half * 128 + li * 64 + rA) * K + k + cS,
                       ApH(buf, half) + li * 4096 + ldsOff);
    };
    auto stB = [&](int buf, int half, int k) {
#pragma unroll
        for (int li = 0; li < 2; ++li)
            async_cp16(B + (size_t)(n0 + half * 128 + li * 64 + rA) * K + k + cS,
                       BpH(buf, half) + li * 4096 + ldsOff);
    };

    stA(0, 0, 0); stB(0, 0, 0); stB(0, 1, 0); stA(0, 1, 0);
    stA(1, 0, 64); stB(1, 0, 64); stB(1, 1, 64);
    VM6();
    BAR();

    const int niter = K >> 7;
#pragma unroll 1
    for (int t = 0; t < niter - 1; ++t) {
        const int kb1 = (t << 7) + 64;
        const int kn  = (t + 1) << 7;
        const int kn2 = kn + 64;
        // P1
        ld_fa(fa, ApH(0, 0), wm, lr, c0, c1);
        ld_fb(fbl, BpH(0, 0), wn, lr, c0, c1);
        stA(1, 1, kb1);
        LGKM8();
        BAR(); LGKM0();
        PRIO1(); quad_mfma<0, 0>(acc, fa, fbl); PRIO0();
        BAR();
        // P2
        ld_fb(fbh, BpH(0, 1), wn, lr, c0, c1);
        stA(0, 0, kn);
        BAR(); LGKM0();
        PRIO1(); quad_mfma<0, 1>(acc, fa, fbh); PRIO0();
        BAR();
        // P3
        ld_fa(fa, ApH(0, 1), wm, lr, c0, c1);
        stB(0, 0, kn);
        BAR(); LGKM0();
        PRIO1(); quad_mfma<1, 1>(acc, fa, fbh); PRIO0();
        BAR();
        // P4
        stB(0, 1, kn);
        VM6();
        BAR();
        PRIO1(); quad_mfma<1, 0>(acc, fa, fbl); PRIO0();
        BAR();
        // P5
        ld_fa(fa, ApH(1, 0), wm, lr, c0, c1);
        ld_fb(fbl, BpH(1, 0), wn, lr, c0, c1);
        stA(0, 1, kn);
        LGKM8();
        BAR(); LGKM0();
        PRIO1(); quad_mfma<0, 0>(acc, fa, fbl); PRIO0();
        BAR();
        // P6
        ld_fb(fbh, BpH(1, 1), wn, lr, c0, c1);
        stA(1, 0, kn2);
        BAR(); LGKM0();
        PRIO1(); quad_mfma<0, 1>(acc, fa, fbh); PRIO0();
        BAR();
        // P7
        ld_fa(fa, ApH(1, 1), wm, lr, c0, c1);
        stB(1, 0, kn2);
        BAR(); LGKM0();
        PRIO1(); quad_mfma<1, 1>(acc, fa, fbh); PRIO0();
        BAR();
        // P8
        stB(1, 1, kn2);
        VM6();
        BAR();
        PRIO1(); quad_mfma<1, 0>(acc, fa, fbl); PRIO0();
        BAR();
    }
    // epilogue iteration
    {
        const int kb1 = ((niter - 1) << 7) + 64;
        ld_fa(fa, ApH(0, 0), wm, lr, c0, c1);
        ld_fb(fbl, BpH(0, 0), wn, lr, c0, c1);
        stA(1, 1, kb1);
        LGKM8();
        BAR(); LGKM0();
        PRIO1(); quad_mfma<0, 0>(acc, fa, fbl); PRIO0();
        BAR();
        ld_fb(fbh, BpH(0, 1), wn, lr, c0, c1);
        BAR(); LGKM0();
        PRIO1(); quad_mfma<0, 1>(acc, fa, fbh); PRIO0();
        BAR();
        ld_fa(fa, ApH(0, 1), wm, lr, c0, c1);
        BAR(); LGKM0();
        PRIO1(); quad_mfma<1, 1>(acc, fa, fbh); PRIO0();
        BAR();
        VM0();
        BAR();
        PRIO1(); quad_mfma<1, 0>(acc, fa, fbl); PRIO0();
        BAR();
        ld_fa(fa, ApH(1, 0), wm, lr, c0, c1);
        ld_fb(fbl, BpH(1, 0), wn, lr, c0, c1);
        BAR(); LGKM0();
        PRIO1(); quad_mfma<0, 0>(acc, fa, fbl); PRIO0();
        BAR();
        ld_fb(fbh, BpH(1, 1), wn, lr, c0, c1);
        BAR(); LGKM0();
        PRIO1(); quad_mfma<0, 1>(acc, fa, fbh); PRIO0();
        BAR();
        ld_fa(fa, ApH(1, 1), wm, lr, c0, c1);
        BAR(); LGKM0();
        PRIO1(); quad_mfma<1, 1>(acc, fa, fbh); PRIO0();
        BAR();
        PRIO1(); quad_mfma<1, 0>(acc, fa, fbl); PRIO0();
    }

    const int rbase = (lane >> 4) * 4;
    if (SCANEPI) {
        // ---- fused local scan ----
        BAR();
#pragma unroll
        for (int mh = 0; mh < 2; ++mh)
#pragma unroll
            for (int nh = 0; nh < 2; ++nh)
#pragma unroll
                for (int mi = 0; mi < 4; ++mi)
#pragma unroll
                    for (int ni = 0; ni < 2; ++ni) {
                        const int cl = nh * 128 + wn * 32 + ni * 16 + lr;
#pragma unroll
                        for (int j = 0; j < 4; ++j) {
                            const int rl = mh * 128 + wm * 64 + mi * 16 + rbase + j;
                            smem[rl * HS_STRIDE + cl] = f2bf(acc[mh][nh][mi][ni][j]);
                        }
                    }
        BAR();
        const int chunk = tid >> 7;
        const int p = tid & 127;
        const int jg = (n0 >> 1) + p;
        float lr_, lr2_, cr_;
        pair_coef(lam, jg, lr_, lr2_, cr_);
        uint_t* gout = reinterpret_cast<uint_t*>((ushort_t*)Cv +
                        (size_t)(m0 + chunk * TC) * NSPEC) + jg;
        float er = 0.0f, ei = 0.0f;
        for (int t = 0; t < TC; ++t) {
            const uint_t v = *reinterpret_cast<const uint_t*>(
                &smem[(chunk * TC + t) * HS_STRIDE + 2 * p]);
            const float ur = bf2f((ushort_t)(v & 0xFFFF));
            const float ui = bf2f((ushort_t)(v >> 16));
            const float nr = fmaf(lr_, er, fmaf(-cr_, ei, ur));
            const float ni = fmaf(lr2_, ei, fmaf(cr_, er, ui));
            gout[(size_t)t * NPAIR] = (uint_t)f2bf(nr) | ((uint_t)f2bf(ni) << 16);
            er = nr; ei = ni;
        }
        const int b = m0 >> 11;
        const int cg = ((m0 & 2047) >> 6) + chunk;
        G[(size_t)(b * NC + cg) * NPAIR + jg] = make_float2(er, ei);
    } else {
        float* C = (float*)Cv;
        const bool du = (*dflag != 0);
#pragma unroll
        for (int mh = 0; mh < 2; ++mh)
#pragma unroll
            for (int nh = 0; nh < 2; ++nh)
#pragma unroll
                for (int mi = 0; mi < 4; ++mi)
#pragma unroll
                    for (int ni = 0; ni < 2; ++ni) {
                        const int col = n0 + nh * 128 + wn * 32 + ni * 16 + lr;
#pragma unroll
                        for (int j = 0; j < 4; ++j) {
                            const int row = m0 + mh * 128 + wm * 64 + mi * 16 + rbase + j;
                            float v = acc[mh][nh][mi][ni][j];
                            if (du) v = fmaf(Dv[col], uu[(size_t)row * DMODEL + col], v);
                            C[(size_t)row * DMODEL + col] = v;
                        }
                    }
    }
}

// ---------------------------------------------------------------------------
// carry (inline, from G) + broadcast: H[t] += Λ^{t+1}·E_c  (in place, bf16)
// grid covers c = 1..31 only; c is uniform per block.
// ---------------------------------------------------------------------------
__global__ __launch_bounds__(256) void scan_applyc(ushort_t* __restrict__ UHb,
                                                   const float* __restrict__ lam,
                                                   const float2* __restrict__ G) {
    const int gid = blockIdx.x * 256 + threadIdx.x;   // BATCH*31*NPAIR
    const int j = gid & (NPAIR - 1);
    const int s9 = gid >> 9;
    const int c = 1 + s9 % 31;
    const int b = s9 / 31;
    float lr, lr2, cr;
    pair_coef(lam, j, lr, lr2, cr);
    // P = Λ^64 via 6 closed-form squarings
    float pr = lr, pr2 = lr2, pc = cr;
    for (int s = 0; s < 6; ++s) {
        const float nr  = pr * pr - pc * pc;
        const float nr2 = pr2 * pr2 - pc * pc;
        const float npc = pc * (pr + pr2);
        pr = nr; pr2 = nr2; pc = npc;
    }
    // carry into chunk c: E = P·E + G[c'] over c' = 0..c-1  (G is L2-resident)
    float er = 0.0f, ei = 0.0f;
    for (int cp = 0; cp < c; ++cp) {
        const float2 g = G[(size_t)(b * NC + cp) * NPAIR + j];
        const float nr = fmaf(pr, er, fmaf(-pc, ei, g.x));
        const float ni = fmaf(pr2, ei, fmaf(pc, er, g.y));
        er = nr; ei = ni;
    }
    // s = Λ^{t+1}·E, iterated
    float sr = fmaf(lr, er, -cr * ei);
    float si = fmaf(lr2, ei, cr * er);
    uint_t* base = reinterpret_cast<uint_t*>(
        UHb + (size_t)(b * SEQLEN + c * TC) * NSPEC) + j;
    for (int t = 0; t < TC; ++t) {
        const uint_t v = base[(size_t)t * NPAIR];
        const float hr = bf2f((ushort_t)(v & 0xFFFF)) + sr;
        const float hi = bf2f((ushort_t)(v >> 16)) + si;
        base[(size_t)t * NPAIR] = (uint_t)f2bf(hr) | ((uint_t)f2bf(hi) << 16);
        const float nsr = fmaf(lr, sr, -cr * si);
        const float nsi = fmaf(lr2, si, cr * sr);
        sr = nsr; si = nsi;
    }
}

// ---------------------------------------------------------------------------
extern "C" void kernel_launch(void* const* d_in, const int* in_sizes, int n_in,
                              void* d_out, int out_size, void* d_ws, size_t ws_size,
                              hipStream_t stream) {
    const float* u  = (const float*)d_in[0];  // [B][S][D]
    const float* ap = (const float*)d_in[1];  // [512]
    const float* Bw = (const float*)d_in[2];  // [N][D]
    const float* Cw = (const float*)d_in[3];  // [D][N]
    const float* Dv = (const float*)d_in[4];  // [D]
    float* out = (float*)d_out;               // [B][S][D]

    char* ws = (char*)d_ws;
    size_t off = 0;
    auto carve = [&](size_t bytes) { char* p = ws + off; off += (bytes + 255) & ~(size_t)255; return p; };

    ushort_t* UHb  = (ushort_t*)carve((size_t)BT_ROWS * NSPEC * sizeof(ushort_t));  // 33.6 MB
    ushort_t* ub   = (ushort_t*)carve((size_t)BT_ROWS * DMODEL * sizeof(ushort_t)); // 33.6 MB
    ushort_t* T1b  = (ushort_t*)carve((size_t)NSPEC * DMODEL * sizeof(ushort_t));
    ushort_t* T2b  = (ushort_t*)carve((size_t)NSPEC * DMODEL * sizeof(ushort_t));
    ushort_t* BwTb = (ushort_t*)carve((size_t)DMODEL * DMODEL * sizeof(ushort_t));
    ushort_t* Cwb  = (ushort_t*)carve((size_t)DMODEL * DMODEL * sizeof(ushort_t));
    ushort_t* W1b  = (ushort_t*)carve((size_t)NSPEC * DMODEL * sizeof(ushort_t));
    ushort_t* W2b  = (ushort_t*)carve((size_t)DMODEL * NSPEC * sizeof(ushort_t));
    float*    lam  = (float*)   carve(NSPEC * sizeof(float));
    int*      dflag= (int*)     carve(sizeof(int));
    float2*   G    = (float2*)  carve((size_t)BATCH * NC * NPAIR * sizeof(float2));

    // 1) lambda + dflag + trig matrices + Bw transpose + Cw conversion
    prep_all<<<1 + 2 * NB_T + NB_TR + NB_CW, 256, 0, stream>>>(
        ap, lam, Dv, dflag, Cw, Cwb, Bw, BwTb, T1b, T2b);

    // 2) u -> bf16 overlapped with both weight GEMMs (one dispatch)
    conv_and_gemm128<<<128 + NB_U, 256, 0, stream>>>(
        u, ub, T1b, BwTb, W1b, Cwb, T2b, W2b);

    // 3) GEMM-U + fused local scan
    {
        dim3 g(BT_ROWS / 256, NSPEC / 256);
        gemm256<true><<<g, 512, 0, stream>>>(ub, W1b, UHb,
            BT_ROWS, DMODEL, nullptr, nullptr, dflag, lam, G);
    }

    // 4) inline carry + broadcast (c = 1..31)
    scan_applyc<<<BATCH * 31 * NPAIR / 256, 256, 0, stream>>>(UHb, lam, G);

    // 5) y = UHb @ W2b^T + D*u
    {
        dim3 g(BT_ROWS / 256, DMODEL / 256);
        gemm256<false><<<g, 512, 0, stream>>>(UHb, W2b, out,
            BT_ROWS, NSPEC, u, Dv, dflag, lam, nullptr);
    }
}

// Round 12
// 155.770 us; speedup vs baseline: 1.0468x; 1.0468x over previous
//
#include <hip/hip_runtime.h>
#include <math.h>

// Problem constants
#define BATCH   8
#define SEQLEN  2048
#define DMODEL  1024
#define KFREQ   513
#define NSPEC   1024       // pair layout: col 2j=Re_j, col 2j+1=Im_j (j=1..511); col1 = Re_512
#define NPAIR   512
#define BT_ROWS (BATCH*SEQLEN)   // 16384
#define NC      32
#define TC      64

static_assert(NC * TC == SEQLEN, "chunking must cover SEQLEN");

typedef __attribute__((ext_vector_type(4))) float f32x4;
typedef __attribute__((ext_vector_type(8))) short bf16x8;
typedef unsigned short ushort_t;
typedef unsigned int uint_t;

__device__ __forceinline__ ushort_t f2bf(float f) {
    union { float f; unsigned u; } v; v.f = f;
    unsigned r = v.u + 0x7FFFu + ((v.u >> 16) & 1u);   // RNE
    return (ushort_t)(r >> 16);
}
__device__ __forceinline__ float bf2f(ushort_t b) {
    union { unsigned u; float f; } v; v.u = ((unsigned)b) << 16;
    return v.f;
}

__device__ __forceinline__ void async_cp16(const void* g, void* l) {
    __builtin_amdgcn_global_load_lds(
        (const __attribute__((address_space(1))) void*)g,
        (__attribute__((address_space(3))) void*)l, 16, 0, 0);
}

#define BAR()   __builtin_amdgcn_s_barrier()
#define PRIO1() __builtin_amdgcn_s_setprio(1)
#define PRIO0() __builtin_amdgcn_s_setprio(0)
#define LGKM0() asm volatile("s_waitcnt lgkmcnt(0)" ::: "memory")
#define LGKM8() asm volatile("s_waitcnt lgkmcnt(8)" ::: "memory")
#define VM6()   asm volatile("s_waitcnt vmcnt(6)" ::: "memory")
#define VM0()   asm volatile("s_waitcnt vmcnt(0)" ::: "memory")

#define SINSTEP 0.00613592315154256491887f   // 2*pi/1024

// ---------------------------------------------------------------------------
// prep_all — one dispatch:
//  bid 0                    : lambda (pair layout) + dflag  [ap cached in LDS,
//                             4-way split accumulator chain]
//  bid 1 .. 2*NB_T          : trig matrices T1b (mode0) / T2b (mode1)
//  next NB_TR               : Bw transpose-convert
//  next NB_CW               : Cw -> bf16
// ---------------------------------------------------------------------------
#define NB_T  (NSPEC * DMODEL / 8 / 256)     // 512 per mode
#define NB_TR 256
#define NB_CW (DMODEL * DMODEL / 8 / 256)    // 512
#define NB_U  (BT_ROWS * DMODEL / 8 / 256)   // 8192

__global__ __launch_bounds__(256) void prep_all(const float* __restrict__ ap,
                                                float* __restrict__ lam,
                                                const float* __restrict__ Dv,
                                                int* __restrict__ dflag,
                                                const float* __restrict__ Cw,
                                                ushort_t* __restrict__ Cwb,
                                                const float* __restrict__ Bw,
                                                ushort_t* __restrict__ BwTb,
                                                ushort_t* __restrict__ T1b,
                                                ushort_t* __restrict__ T2b) {
    const int bid = blockIdx.x;
    if (bid == 0) {
        // --- lambda + dflag: ap staged to LDS, 4-way partial sums ---
        __shared__ float stab[1024];
        __shared__ float apl[512];
        __shared__ int anyd;
        if (threadIdx.x == 0) anyd = 0;
        for (int j = threadIdx.x; j < 1024; j += 256)
            stab[j] = sinf((float)j * SINSTEP);
        for (int j = threadIdx.x; j < 511; j += 256)
            apl[j] = ap[j];
        __syncthreads();
        for (int q = threadIdx.x; q < 1024; q += 256)
            if (Dv[q] != 0.0f) anyd = 1;            // benign race
        for (int f = threadIdx.x; f < KFREQ; f += 256) {
            float o0 = 0.0f, o1 = 0.0f, o2 = 0.0f, o3 = 0.0f;
            int j = 1;
            for (; j + 3 <= 511; j += 4) {
                o0 = fmaf(apl[j - 1], stab[(j * f) & 1023], o0);
                o1 = fmaf(apl[j],     stab[((j + 1) * f) & 1023], o1);
                o2 = fmaf(apl[j + 1], stab[((j + 2) * f) & 1023], o2);
                o3 = fmaf(apl[j + 2], stab[((j + 3) * f) & 1023], o3);
            }
            for (; j <= 511; ++j)
                o0 = fmaf(apl[j - 1], stab[(j * f) & 1023], o0);
            const float om = ((o0 + o1) + (o2 + o3)) * -2.0f;
            const float w2 = om * om;
            const float den = 1.0f + w2;
            const float re = (1.0f - w2) / den;
            const float im = -2.0f * om / den;
            if (f == 0)        lam[0] = re;
            else if (f == 512) lam[1] = re;
            else { lam[2 * f] = re; lam[2 * f + 1] = im; }
        }
        __syncthreads();
        if (threadIdx.x == 0) *dflag = anyd;
    } else if (bid < 1 + 2 * NB_T) {
        // --- trig matrix, pair-layout rows ---
        __shared__ float stab[1024];
        for (int j = threadIdx.x; j < 1024; j += 256)
            stab[j] = sinf((float)j * SINSTEP);
        __syncthreads();
        const int t = bid - 1;
        const int mode = t >= NB_T;
        ushort_t* T = mode ? T2b : T1b;
        const int i = (t - mode * NB_T) * 256 + threadIdx.x;
        const int row = i >> 7;
        const int nb  = (i & 127) << 3;
        const int kf  = (row == 1) ? 512 : (row >> 1);
        const bool sb = (row & 1) && (row != 1);        // sine basis?
        float scale = 1.0f;
        if (mode) scale = ((row < 2) ? 1.0f : 2.0f) / 1024.0f;
        ushort_t o[8];
        int m = (kf * nb) & 1023;
#pragma unroll
        for (int j = 0; j < 8; ++j) {
            const float v = sb ? -stab[m] : stab[(m + 256) & 1023];
            o[j] = f2bf(v * scale);
            m = (m + kf) & 1023;
        }
        reinterpret_cast<bf16x8*>(T)[i] = *reinterpret_cast<bf16x8*>(o);
    } else if (bid < 1 + 2 * NB_T + NB_TR) {
        // --- Bw transpose-convert ---
        __shared__ float tile[64][65];
        const int b2 = bid - (1 + 2 * NB_T);
        const int bx = (b2 & 15) * 64;
        const int by = (b2 >> 4) * 64;
        const int lx = threadIdx.x & 63;
        const int ly = threadIdx.x >> 6;
#pragma unroll
        for (int i = 0; i < 16; ++i) {
            const int r = ly + i * 4;
            tile[r][lx] = Bw[(size_t)(by + r) * DMODEL + bx + lx];
        }
        __syncthreads();
#pragma unroll
        for (int i = 0; i < 16; ++i) {
            const int r = ly + i * 4;
            BwTb[(size_t)(bx + r) * DMODEL + by + lx] = f2bf(tile[lx][r]);
        }
    } else {
        // --- Cw -> bf16 ---
        const int b3 = bid - (1 + 2 * NB_T + NB_TR);
        const int i = b3 * 256 + threadIdx.x;
        const float4 a = reinterpret_cast<const float4*>(Cw)[2 * i];
        const float4 b = reinterpret_cast<const float4*>(Cw)[2 * i + 1];
        ushort_t o[8] = {f2bf(a.x), f2bf(a.y), f2bf(a.z), f2bf(a.w),
                         f2bf(b.x), f2bf(b.y), f2bf(b.z), f2bf(b.w)};
        reinterpret_cast<bf16x8*>(Cwb)[i] = *reinterpret_cast<bf16x8*>(o);
    }
}

// ---------------------------------------------------------------------------
// conv_and_gemm128 — one dispatch: first 128 blocks run the two 128x128 BK=32
// weight GEMMs; remaining 8192 blocks convert u -> bf16 (BW-bound) and fill
// the idle CUs.
// ---------------------------------------------------------------------------
__global__ __launch_bounds__(256) void conv_and_gemm128(
        const float* __restrict__ u, ushort_t* __restrict__ ub,
        const ushort_t* __restrict__ A0, const ushort_t* __restrict__ B0,
        ushort_t* __restrict__ C0,
        const ushort_t* __restrict__ A1, const ushort_t* __restrict__ B1,
        ushort_t* __restrict__ C1) {
    const int bid = blockIdx.x;
    if (bid >= 128) {
        // --- u -> bf16 ---
        const int i = (bid - 128) * 256 + threadIdx.x;
        const float4 a = reinterpret_cast<const float4*>(u)[2 * i];
        const float4 b = reinterpret_cast<const float4*>(u)[2 * i + 1];
        ushort_t o[8] = {f2bf(a.x), f2bf(a.y), f2bf(a.z), f2bf(a.w),
                         f2bf(b.x), f2bf(b.y), f2bf(b.z), f2bf(b.w)};
        reinterpret_cast<bf16x8*>(ub)[i] = *reinterpret_cast<bf16x8*>(o);
        return;
    }
    // --- 128x128 BK=32 GEMM, z = bid>>6 selects operand triple ---
    const int K = 1024, N = 1024;
    const int z = bid >> 6;
    const ushort_t* A = z ? A1 : A0;
    const ushort_t* B = z ? B1 : B0;
    ushort_t*       C = z ? C1 : C0;
    const int g = bid & 63;
    const int m0 = (g >> 3) * 128;
    const int n0 = (g & 7) * 128;
    __shared__ ushort_t As[128 * 32];
    __shared__ ushort_t Bs[128 * 32];
    const int tid  = threadIdx.x;
    const int lane = tid & 63;
    const int w    = tid >> 6;
    const int wr = (w >> 1) * 64;
    const int wc = (w & 1) * 64;

    f32x4 acc[4][4] = {};

    const int pos  = w * 512 + lane * 8;
    const int srow = pos >> 5;
    const int scol = pos & 31;
    const int lr = lane & 15;
    const int lk = (lane >> 4) * 8;

    for (int k0 = 0; k0 < K; k0 += 32) {
        __syncthreads();
        async_cp16(A + (size_t)(m0 + srow)      * K + k0 + scol, As + w * 512);
        async_cp16(A + (size_t)(m0 + srow + 64) * K + k0 + scol, As + 2048 + w * 512);
        async_cp16(B + (size_t)(n0 + srow)      * K + k0 + scol, Bs + w * 512);
        async_cp16(B + (size_t)(n0 + srow + 64) * K + k0 + scol, Bs + 2048 + w * 512);
        __syncthreads();

        bf16x8 fa[4], fb[4];
#pragma unroll
        for (int mi = 0; mi < 4; ++mi)
            fa[mi] = *reinterpret_cast<const bf16x8*>(&As[(wr + mi * 16 + lr) * 32 + lk]);
#pragma unroll
        for (int ni = 0; ni < 4; ++ni)
            fb[ni] = *reinterpret_cast<const bf16x8*>(&Bs[(wc + ni * 16 + lr) * 32 + lk]);
#pragma unroll
        for (int mi = 0; mi < 4; ++mi)
#pragma unroll
            for (int ni = 0; ni < 4; ++ni)
                acc[mi][ni] = __builtin_amdgcn_mfma_f32_16x16x32_bf16(
                    fa[mi], fb[ni], acc[mi][ni], 0, 0, 0);
    }

    const int rbase = (lane >> 4) * 4;
#pragma unroll
    for (int mi = 0; mi < 4; ++mi)
#pragma unroll
        for (int ni = 0; ni < 4; ++ni) {
            const int col = n0 + wc + ni * 16 + lr;
#pragma unroll
            for (int j = 0; j < 4; ++j) {
                const int row = m0 + wr + mi * 16 + rbase + j;
                C[(size_t)row * N + col] = f2bf(acc[mi][ni][j]);
            }
        }
}

// ---------------------------------------------------------------------------
// Generalized pair recurrence coefficients (j=0 packs DC + Nyquist reals).
// ---------------------------------------------------------------------------
__device__ __forceinline__ void pair_coef(const float* lam, int j,
                                          float& lr, float& lr2, float& cr) {
    const float a = lam[2 * j];
    const float b = lam[2 * j + 1];
    if (j == 0) { lr = a; lr2 = b; cr = 0.0f; }
    else        { lr = a; lr2 = a; cr = b; }
}

// ---------------------------------------------------------------------------
// 256x256 8-wave bf16 MFMA GEMM — m201-style 8-phase schedule (round-8 proven;
// epilogue switched by SCANEPI). Byte-identical to round 10.
// ---------------------------------------------------------------------------
template <int MH, int NH>
__device__ __forceinline__ void quad_mfma(f32x4 (&acc)[2][2][4][2],
                                          const bf16x8 (&fa)[4][2],
                                          const bf16x8 (&fb)[2][2]) {
#pragma unroll
    for (int mi = 0; mi < 4; ++mi)
#pragma unroll
        for (int ni = 0; ni < 2; ++ni) {
            acc[MH][NH][mi][ni] = __builtin_amdgcn_mfma_f32_16x16x32_bf16(
                fa[mi][0], fb[ni][0], acc[MH][NH][mi][ni], 0, 0, 0);
            acc[MH][NH][mi][ni] = __builtin_amdgcn_mfma_f32_16x16x32_bf16(
                fa[mi][1], fb[ni][1], acc[MH][NH][mi][ni], 0, 0, 0);
        }
}

__device__ __forceinline__ void ld_fa(bf16x8 (&fa)[4][2], const ushort_t* hb,
                                      int wm, int lr, int c0, int c1) {
#pragma unroll
    for (int mi = 0; mi < 4; ++mi) {
        const ushort_t* p = hb + (wm * 64 + mi * 16 + lr) * 64;
        fa[mi][0] = *reinterpret_cast<const bf16x8*>(p + c0);
        fa[mi][1] = *reinterpret_cast<const bf16x8*>(p + c1);
    }
}
__device__ __forceinline__ void ld_fb(bf16x8 (&fb)[2][2], const ushort_t* hb,
                                      int wn, int lr, int c0, int c1) {
#pragma unroll
    for (int ni = 0; ni < 2; ++ni) {
        const ushort_t* p = hb + (wn * 32 + ni * 16 + lr) * 64;
        fb[ni][0] = *reinterpret_cast<const bf16x8*>(p + c0);
        fb[ni][1] = *reinterpret_cast<const bf16x8*>(p + c1);
    }
}

#define HS_STRIDE 260

template <bool SCANEPI>
__global__ __launch_bounds__(512, 2) void gemm256(const ushort_t* __restrict__ A,
                                                  const ushort_t* __restrict__ B,
                                                  void* __restrict__ Cv,
                                                  int M, int K,
                                                  const float* __restrict__ uu,
                                                  const float* __restrict__ Dv,
                                                  const int* __restrict__ dflag,
                                                  const float* __restrict__ lam,
                                                  float2* __restrict__ G) {
    __shared__ ushort_t smem[66560];   // As/Bs (65536) aliased with Hs
    const int tid  = threadIdx.x;
    const int lane = tid & 63;
    const int w    = tid >> 6;      // 0..7
    const int wm   = w >> 2;        // 0..1
    const int wn   = w & 3;         // 0..3
    const int m0 = blockIdx.x * 256;
    const int n0 = blockIdx.y * 256;
    const int lr = lane & 15;
    const int lk = (lane >> 4) * 8;
    const int xv = (lr & 7) << 3;
    const int c0 = lk ^ xv;
    const int c1 = (32 + lk) ^ xv;

    const int rA = tid >> 3;
    const int cS = ((tid & 7) << 3) ^ ((rA & 7) << 3);
    const int ldsOff = w << 9;

    auto ApH = [&](int buf, int half) { return smem + (buf * 2 + half) * 8192; };
    auto BpH = [&](int buf, int half) { return smem + 32768 + (buf * 2 + half) * 8192; };

    f32x4 acc[2][2][4][2] = {};
    bf16x8 fa[4][2], fbl[2][2], fbh[2][2];

    auto stA = [&](int buf, int half, int k) {
#pragma unroll
        for (int li = 0; li < 2; ++li)
            async_cp16(A + (size_t)(m0 + half * 128 + li * 64 + rA) * K + k + cS,
                       ApH(buf, half) + li * 4096 + ldsOff);
    };
    auto stB = [&](int buf, int half, int k) {
#pragma unroll
        for (int li = 0; li < 2; ++li)
            async_cp16(B + (size_t)(n0 + half * 128 + li * 64 + rA) * K + k + cS,
                       BpH(buf, half) + li * 4096 + ldsOff);
    };

    stA(0, 0, 0); stB(0, 0, 0); stB(0, 1, 0); stA(0, 1, 0);
    stA(1, 0, 64); stB(1, 0, 64); stB(1, 1, 64);
    VM6();
    BAR();

    const int niter = K >> 7;
#pragma unroll 1
    for (int t = 0; t < niter - 1; ++t) {
        const int kb1 = (t << 7) + 64;
        const int kn  = (t + 1) << 7;
        const int kn2 = kn + 64;
        // P1
        ld_fa(fa, ApH(0, 0), wm, lr, c0, c1);
        ld_fb(fbl, BpH(0, 0), wn, lr, c0, c1);
        stA(1, 1, kb1);
        LGKM8();
        BAR(); LGKM0();
        PRIO1(); quad_mfma<0, 0>(acc, fa, fbl); PRIO0();
        BAR();
        // P2
        ld_fb(fbh, BpH(0, 1), wn, lr, c0, c1);
        stA(0, 0, kn);
        BAR(); LGKM0();
        PRIO1(); quad_mfma<0, 1>(acc, fa, fbh); PRIO0();
        BAR();
        // P3
        ld_fa(fa, ApH(0, 1), wm, lr, c0, c1);
        stB(0, 0, kn);
        BAR(); LGKM0();
        PRIO1(); quad_mfma<1, 1>(acc, fa, fbh); PRIO0();
        BAR();
        // P4
        stB(0, 1, kn);
        VM6();
        BAR();
        PRIO1(); quad_mfma<1, 0>(acc, fa, fbl); PRIO0();
        BAR();
        // P5
        ld_fa(fa, ApH(1, 0), wm, lr, c0, c1);
        ld_fb(fbl, BpH(1, 0), wn, lr, c0, c1);
        stA(0, 1, kn);
        LGKM8();
        BAR(); LGKM0();
        PRIO1(); quad_mfma<0, 0>(acc, fa, fbl); PRIO0();
        BAR();
        // P6
        ld_fb(fbh, BpH(1, 1), wn, lr, c0, c1);
        stA(1, 0, kn2);
        BAR(); LGKM0();
        PRIO1(); quad_mfma<0, 1>(acc, fa, fbh); PRIO0();
        BAR();
        // P7
        ld_fa(fa, ApH(1, 1), wm, lr, c0, c1);
        stB(1, 0, kn2);
        BAR(); LGKM0();
        PRIO1(); quad_mfma<1, 1>(acc, fa, fbh); PRIO0();
        BAR();
        // P8
        stB(1, 1, kn2);
        VM6();
        BAR();
        PRIO1(); quad_mfma<1, 0>(acc, fa, fbl); PRIO0();
        BAR();
    }
    // epilogue iteration
    {
        const int kb1 = ((niter - 1) << 7) + 64;
        ld_fa(fa, ApH(0, 0), wm, lr, c0, c1);
        ld_fb(fbl, BpH(0, 0), wn, lr, c0, c1);
        stA(1, 1, kb1);
        LGKM8();
        BAR(); LGKM0();
        PRIO1(); quad_mfma<0, 0>(acc, fa, fbl); PRIO0();
        BAR();
        ld_fb(fbh, BpH(0, 1), wn, lr, c0, c1);
        BAR(); LGKM0();
        PRIO1(); quad_mfma<0, 1>(acc, fa, fbh); PRIO0();
        BAR();
        ld_fa(fa, ApH(0, 1), wm, lr, c0, c1);
        BAR(); LGKM0();
        PRIO1(); quad_mfma<1, 1>(acc, fa, fbh); PRIO0();
        BAR();
        VM0();
        BAR();
        PRIO1(); quad_mfma<1, 0>(acc, fa, fbl); PRIO0();
        BAR();
        ld_fa(fa, ApH(1, 0), wm, lr, c0, c1);
        ld_fb(fbl, BpH(1, 0), wn, lr, c0, c1);
        BAR(); LGKM0();
        PRIO1(); quad_mfma<0, 0>(acc, fa, fbl); PRIO0();
        BAR();
        ld_fb(fbh, BpH(1, 1), wn, lr, c0, c1);
        BAR(); LGKM0();
        PRIO1(); quad_mfma<0, 1>(acc, fa, fbh); PRIO0();
        BAR();
        ld_fa(fa, ApH(1, 1), wm, lr, c0, c1);
        BAR(); LGKM0();
        PRIO1(); quad_mfma<1, 1>(acc, fa, fbh); PRIO0();
        BAR();
        PRIO1(); quad_mfma<1, 0>(acc, fa, fbl); PRIO0();
    }

    const int rbase = (lane >> 4) * 4;
    if (SCANEPI) {
        // ---- fused local scan ----
        BAR();
#pragma unroll
        for (int mh = 0; mh < 2; ++mh)
#pragma unroll
            for (int nh = 0; nh < 2; ++nh)
#pragma unroll
                for (int mi = 0; mi < 4; ++mi)
#pragma unroll
                    for (int ni = 0; ni < 2; ++ni) {
                        const int cl = nh * 128 + wn * 32 + ni * 16 + lr;
#pragma unroll
                        for (int j = 0; j < 4; ++j) {
                            const int rl = mh * 128 + wm * 64 + mi * 16 + rbase + j;
                            smem[rl * HS_STRIDE + cl] = f2bf(acc[mh][nh][mi][ni][j]);
                        }
                    }
        BAR();
        const int chunk = tid >> 7;
        const int p = tid & 127;
        const int jg = (n0 >> 1) + p;
        float lr_, lr2_, cr_;
        pair_coef(lam, jg, lr_, lr2_, cr_);
        uint_t* gout = reinterpret_cast<uint_t*>((ushort_t*)Cv +
                        (size_t)(m0 + chunk * TC) * NSPEC) + jg;
        float er = 0.0f, ei = 0.0f;
        for (int t = 0; t < TC; ++t) {
            const uint_t v = *reinterpret_cast<const uint_t*>(
                &smem[(chunk * TC + t) * HS_STRIDE + 2 * p]);
            const float ur = bf2f((ushort_t)(v & 0xFFFF));
            const float ui = bf2f((ushort_t)(v >> 16));
            const float nr = fmaf(lr_, er, fmaf(-cr_, ei, ur));
            const float ni = fmaf(lr2_, ei, fmaf(cr_, er, ui));
            gout[(size_t)t * NPAIR] = (uint_t)f2bf(nr) | ((uint_t)f2bf(ni) << 16);
            er = nr; ei = ni;
        }
        const int b = m0 >> 11;
        const int cg = ((m0 & 2047) >> 6) + chunk;
        G[(size_t)(b * NC + cg) * NPAIR + jg] = make_float2(er, ei);
    } else {
        float* C = (float*)Cv;
        const bool du = (*dflag != 0);
#pragma unroll
        for (int mh = 0; mh < 2; ++mh)
#pragma unroll
            for (int nh = 0; nh < 2; ++nh)
#pragma unroll
                for (int mi = 0; mi < 4; ++mi)
#pragma unroll
                    for (int ni = 0; ni < 2; ++ni) {
                        const int col = n0 + nh * 128 + wn * 32 + ni * 16 + lr;
#pragma unroll
                        for (int j = 0; j < 4; ++j) {
                            const int row = m0 + mh * 128 + wm * 64 + mi * 16 + rbase + j;
                            float v = acc[mh][nh][mi][ni][j];
                            if (du) v = fmaf(Dv[col], uu[(size_t)row * DMODEL + col], v);
                            C[(size_t)row * DMODEL + col] = v;
                        }
                    }
    }
}

// ---------------------------------------------------------------------------
// carry (inline, from G) + broadcast: H[t] += Λ^{t+1}·E_c  (in place, bf16)
// grid covers c = 1..31 only; c is uniform per block.
// ---------------------------------------------------------------------------
__global__ __launch_bounds__(256) void scan_applyc(ushort_t* __restrict__ UHb,
                                                   const float* __restrict__ lam,
                                                   const float2* __restrict__ G) {
    const int gid = blockIdx.x * 256 + threadIdx.x;   // BATCH*31*NPAIR
    const int j = gid & (NPAIR - 1);
    const int s9 = gid >> 9;
    const int c = 1 + s9 % 31;
    const int b = s9 / 31;
    float lr, lr2, cr;
    pair_coef(lam, j, lr, lr2, cr);
    // P = Λ^64 via 6 closed-form squarings
    float pr = lr, pr2 = lr2, pc = cr;
    for (int s = 0; s < 6; ++s) {
        const float nr  = pr * pr - pc * pc;
        const float nr2 = pr2 * pr2 - pc * pc;
        const float npc = pc * (pr + pr2);
        pr = nr; pr2 = nr2; pc = npc;
    }
    // carry into chunk c: E = P·E + G[c'] over c' = 0..c-1  (G is L2-resident)
    float er = 0.0f, ei = 0.0f;
    for (int cp = 0; cp < c; ++cp) {
        const float2 g = G[(size_t)(b * NC + cp) * NPAIR + j];
        const float nr = fmaf(pr, er, fmaf(-pc, ei, g.x));
        const float ni = fmaf(pr2, ei, fmaf(pc, er, g.y));
        er = nr; ei = ni;
    }
    // s = Λ^{t+1}·E, iterated
    float sr = fmaf(lr, er, -cr * ei);
    float si = fmaf(lr2, ei, cr * er);
    uint_t* base = reinterpret_cast<uint_t*>(
        UHb + (size_t)(b * SEQLEN + c * TC) * NSPEC) + j;
    for (int t = 0; t < TC; ++t) {
        const uint_t v = base[(size_t)t * NPAIR];
        const float hr = bf2f((ushort_t)(v & 0xFFFF)) + sr;
        const float hi = bf2f((ushort_t)(v >> 16)) + si;
        base[(size_t)t * NPAIR] = (uint_t)f2bf(hr) | ((uint_t)f2bf(hi) << 16);
        const float nsr = fmaf(lr, sr, -cr * si);
        const float nsi = fmaf(lr2, si, cr * sr);
        sr = nsr; si = nsi;
    }
}

// ---------------------------------------------------------------------------
extern "C" void kernel_launch(void* const* d_in, const int* in_sizes, int n_in,
                              void* d_out, int out_size, void* d_ws, size_t ws_size,
                              hipStream_t stream) {
    const float* u  = (const float*)d_in[0];  // [B][S][D]
    const float* ap = (const float*)d_in[1];  // [512]
    const float* Bw = (const float*)d_in[2];  // [N][D]
    const float* Cw = (const float*)d_in[3];  // [D][N]
    const float* Dv = (const float*)d_in[4];  // [D]
    float* out = (float*)d_out;               // [B][S][D]

    char* ws = (char*)d_ws;
    size_t off = 0;
    auto carve = [&](size_t bytes) { char* p = ws + off; off += (bytes + 255) & ~(size_t)255; return p; };

    ushort_t* UHb  = (ushort_t*)carve((size_t)BT_ROWS * NSPEC * sizeof(ushort_t));  // 33.6 MB
    ushort_t* ub   = (ushort_t*)carve((size_t)BT_ROWS * DMODEL * sizeof(ushort_t)); // 33.6 MB
    ushort_t* T1b  = (ushort_t*)carve((size_t)NSPEC * DMODEL * sizeof(ushort_t));
    ushort_t* T2b  = (ushort_t*)carve((size_t)NSPEC * DMODEL * sizeof(ushort_t));
    ushort_t* BwTb = (ushort_t*)carve((size_t)DMODEL * DMODEL * sizeof(ushort_t));
    ushort_t* Cwb  = (ushort_t*)carve((size_t)DMODEL * DMODEL * sizeof(ushort_t));
    ushort_t* W1b  = (ushort_t*)carve((size_t)NSPEC * DMODEL * sizeof(ushort_t));
    ushort_t* W2b  = (ushort_t*)carve((size_t)DMODEL * NSPEC * sizeof(ushort_t));
    float*    lam  = (float*)   carve(NSPEC * sizeof(float));
    int*      dflag= (int*)     carve(sizeof(int));
    float2*   G    = (float2*)  carve((size_t)BATCH * NC * NPAIR * sizeof(float2));

    // 1) lambda + dflag + trig matrices + Bw transpose + Cw conversion
    prep_all<<<1 + 2 * NB_T + NB_TR + NB_CW, 256, 0, stream>>>(
        ap, lam, Dv, dflag, Cw, Cwb, Bw, BwTb, T1b, T2b);

    // 2) u -> bf16 overlapped with both weight GEMMs (one dispatch)
    conv_and_gemm128<<<128 + NB_U, 256, 0, stream>>>(
        u, ub, T1b, BwTb, W1b, Cwb, T2b, W2b);

    // 3) GEMM-U + fused local scan
    {
        dim3 g(BT_ROWS / 256, NSPEC / 256);
        gemm256<true><<<g, 512, 0, stream>>>(ub, W1b, UHb,
            BT_ROWS, DMODEL, nullptr, nullptr, dflag, lam, G);
    }

    // 4) inline carry + broadcast (c = 1..31)
    scan_applyc<<<BATCH * 31 * NPAIR / 256, 256, 0, stream>>>(UHb, lam, G);

    // 5) y = UHb @ W2b^T + D*u
    {
        dim3 g(BT_ROWS / 256, DMODEL / 256);
        gemm256<false><<<g, 512, 0, stream>>>(UHb, W2b, out,
            BT_ROWS, NSPEC, u, Dv, dflag, lam, nullptr);
    }
}

// Round 13
// 145.496 us; speedup vs baseline: 1.1207x; 1.0706x over previous
//
#include <hip/hip_runtime.h>
#include <math.h>

// Problem constants
#define BATCH   8
#define SEQLEN  2048
#define DMODEL  1024
#define KFREQ   513
#define NSPEC   1024       // pair layout: col 2j=Re_j, col 2j+1=Im_j (j=1..511); col1 = Re_512
#define NPAIR   512
#define BT_ROWS (BATCH*SEQLEN)   // 16384
#define NC      32
#define TC      64

static_assert(NC * TC == SEQLEN, "chunking must cover SEQLEN");

typedef __attribute__((ext_vector_type(4))) float f32x4;
typedef __attribute__((ext_vector_type(8))) short bf16x8;
typedef unsigned short ushort_t;
typedef unsigned int uint_t;

__device__ __forceinline__ ushort_t f2bf(float f) {
    union { float f; unsigned u; } v; v.f = f;
    unsigned r = v.u + 0x7FFFu + ((v.u >> 16) & 1u);   // RNE
    return (ushort_t)(r >> 16);
}
__device__ __forceinline__ float bf2f(ushort_t b) {
    union { unsigned u; float f; } v; v.u = ((unsigned)b) << 16;
    return v.f;
}

__device__ __forceinline__ void async_cp16(const void* g, void* l) {
    __builtin_amdgcn_global_load_lds(
        (const __attribute__((address_space(1))) void*)g,
        (__attribute__((address_space(3))) void*)l, 16, 0, 0);
}

#define BAR()   __builtin_amdgcn_s_barrier()
#define PRIO1() __builtin_amdgcn_s_setprio(1)
#define PRIO0() __builtin_amdgcn_s_setprio(0)
#define LGKM0() asm volatile("s_waitcnt lgkmcnt(0)" ::: "memory")
#define LGKM8() asm volatile("s_waitcnt lgkmcnt(8)" ::: "memory")
#define VM6()   asm volatile("s_waitcnt vmcnt(6)" ::: "memory")
#define VM0()   asm volatile("s_waitcnt vmcnt(0)" ::: "memory")

#define SINSTEP 0.00613592315154256491887f   // 2*pi/1024

// ---------------------------------------------------------------------------
// prep_all — one dispatch (round-10 structure + fast lambda):
//  bid 0                        : lambda (pair layout) + dflag  [ap in LDS,
//                                 4-way split accumulator chain]
//  bid 1 .. 2*NB_T              : trig matrices T1b (mode0) / T2b (mode1)
//  next NB_TR                   : Bw transpose-convert
//  next NB_CW                   : Cw -> bf16
//  next NB_U                    : u -> bf16
// ---------------------------------------------------------------------------
#define NB_T  (NSPEC * DMODEL / 8 / 256)     // 512 per mode
#define NB_TR 256
#define NB_CW (DMODEL * DMODEL / 8 / 256)    // 512
#define NB_U  (BT_ROWS * DMODEL / 8 / 256)   // 8192

__global__ __launch_bounds__(256) void prep_all(const float* __restrict__ ap,
                                                float* __restrict__ lam,
                                                const float* __restrict__ Dv,
                                                int* __restrict__ dflag,
                                                const float* __restrict__ Cw,
                                                ushort_t* __restrict__ Cwb,
                                                const float* __restrict__ Bw,
                                                ushort_t* __restrict__ BwTb,
                                                ushort_t* __restrict__ T1b,
                                                ushort_t* __restrict__ T2b,
                                                const float* __restrict__ u,
                                                ushort_t* __restrict__ ub) {
    const int bid = blockIdx.x;
    if (bid == 0) {
        // --- lambda + dflag: ap staged to LDS, 4-way partial sums ---
        __shared__ float stab[1024];
        __shared__ float apl[512];
        __shared__ int anyd;
        if (threadIdx.x == 0) anyd = 0;
        for (int j = threadIdx.x; j < 1024; j += 256)
            stab[j] = sinf((float)j * SINSTEP);
        for (int j = threadIdx.x; j < 511; j += 256)
            apl[j] = ap[j];
        __syncthreads();
        for (int q = threadIdx.x; q < 1024; q += 256)
            if (Dv[q] != 0.0f) anyd = 1;            // benign race
        for (int f = threadIdx.x; f < KFREQ; f += 256) {
            float o0 = 0.0f, o1 = 0.0f, o2 = 0.0f, o3 = 0.0f;
            int j = 1;
            for (; j + 3 <= 511; j += 4) {
                o0 = fmaf(apl[j - 1], stab[(j * f) & 1023], o0);
                o1 = fmaf(apl[j],     stab[((j + 1) * f) & 1023], o1);
                o2 = fmaf(apl[j + 1], stab[((j + 2) * f) & 1023], o2);
                o3 = fmaf(apl[j + 2], stab[((j + 3) * f) & 1023], o3);
            }
            for (; j <= 511; ++j)
                o0 = fmaf(apl[j - 1], stab[(j * f) & 1023], o0);
            const float om = ((o0 + o1) + (o2 + o3)) * -2.0f;
            const float w2 = om * om;
            const float den = 1.0f + w2;
            const float re = (1.0f - w2) / den;
            const float im = -2.0f * om / den;
            if (f == 0)        lam[0] = re;
            else if (f == 512) lam[1] = re;
            else { lam[2 * f] = re; lam[2 * f + 1] = im; }
        }
        __syncthreads();
        if (threadIdx.x == 0) *dflag = anyd;
    } else if (bid < 1 + 2 * NB_T) {
        // --- trig matrix, pair-layout rows ---
        __shared__ float stab[1024];
        for (int j = threadIdx.x; j < 1024; j += 256)
            stab[j] = sinf((float)j * SINSTEP);
        __syncthreads();
        const int t = bid - 1;
        const int mode = t >= NB_T;
        ushort_t* T = mode ? T2b : T1b;
        const int i = (t - mode * NB_T) * 256 + threadIdx.x;
        const int row = i >> 7;
        const int nb  = (i & 127) << 3;
        const int kf  = (row == 1) ? 512 : (row >> 1);
        const bool sb = (row & 1) && (row != 1);        // sine basis?
        float scale = 1.0f;
        if (mode) scale = ((row < 2) ? 1.0f : 2.0f) / 1024.0f;
        ushort_t o[8];
        int m = (kf * nb) & 1023;
#pragma unroll
        for (int j = 0; j < 8; ++j) {
            const float v = sb ? -stab[m] : stab[(m + 256) & 1023];
            o[j] = f2bf(v * scale);
            m = (m + kf) & 1023;
        }
        reinterpret_cast<bf16x8*>(T)[i] = *reinterpret_cast<bf16x8*>(o);
    } else if (bid < 1 + 2 * NB_T + NB_TR) {
        // --- Bw transpose-convert ---
        __shared__ float tile[64][65];
        const int b2 = bid - (1 + 2 * NB_T);
        const int bx = (b2 & 15) * 64;
        const int by = (b2 >> 4) * 64;
        const int lx = threadIdx.x & 63;
        const int ly = threadIdx.x >> 6;
#pragma unroll
        for (int i = 0; i < 16; ++i) {
            const int r = ly + i * 4;
            tile[r][lx] = Bw[(size_t)(by + r) * DMODEL + bx + lx];
        }
        __syncthreads();
#pragma unroll
        for (int i = 0; i < 16; ++i) {
            const int r = ly + i * 4;
            BwTb[(size_t)(bx + r) * DMODEL + by + lx] = f2bf(tile[lx][r]);
        }
    } else if (bid < 1 + 2 * NB_T + NB_TR + NB_CW) {
        // --- Cw -> bf16 ---
        const int b3 = bid - (1 + 2 * NB_T + NB_TR);
        const int i = b3 * 256 + threadIdx.x;
        const float4 a = reinterpret_cast<const float4*>(Cw)[2 * i];
        const float4 b = reinterpret_cast<const float4*>(Cw)[2 * i + 1];
        ushort_t o[8] = {f2bf(a.x), f2bf(a.y), f2bf(a.z), f2bf(a.w),
                         f2bf(b.x), f2bf(b.y), f2bf(b.z), f2bf(b.w)};
        reinterpret_cast<bf16x8*>(Cwb)[i] = *reinterpret_cast<bf16x8*>(o);
    } else {
        // --- u -> bf16 ---
        const int b4 = bid - (1 + 2 * NB_T + NB_TR + NB_CW);
        const int i = b4 * 256 + threadIdx.x;
        const float4 a = reinterpret_cast<const float4*>(u)[2 * i];
        const float4 b = reinterpret_cast<const float4*>(u)[2 * i + 1];
        ushort_t o[8] = {f2bf(a.x), f2bf(a.y), f2bf(a.z), f2bf(a.w),
                         f2bf(b.x), f2bf(b.y), f2bf(b.z), f2bf(b.w)};
        reinterpret_cast<bf16x8*>(ub)[i] = *reinterpret_cast<bf16x8*>(o);
    }
}

// ---------------------------------------------------------------------------
// 128x128 BK=32 bf16 MFMA GEMM — both weight-precompute GEMMs (blockIdx.z).
// Standalone dispatch (round-10 proven): L2-resident operands, no streaming
// contention from the u-conversion.
// ---------------------------------------------------------------------------
__global__ __launch_bounds__(256) void gemm128z(const ushort_t* __restrict__ A0,
                                                const ushort_t* __restrict__ B0,
                                                ushort_t* __restrict__ C0,
                                                const ushort_t* __restrict__ A1,
                                                const ushort_t* __restrict__ B1,
                                                ushort_t* __restrict__ C1) {
    const int K = 1024, N = 1024;
    const ushort_t* A = blockIdx.z ? A1 : A0;
    const ushort_t* B = blockIdx.z ? B1 : B0;
    ushort_t*       C = blockIdx.z ? C1 : C0;
    __shared__ ushort_t As[128 * 32];
    __shared__ ushort_t Bs[128 * 32];
    const int tid  = threadIdx.x;
    const int lane = tid & 63;
    const int w    = tid >> 6;
    const int m0 = blockIdx.x * 128;
    const int n0 = blockIdx.y * 128;
    const int wr = (w >> 1) * 64;
    const int wc = (w & 1) * 64;

    f32x4 acc[4][4] = {};

    const int pos  = w * 512 + lane * 8;
    const int srow = pos >> 5;
    const int scol = pos & 31;
    const int lr = lane & 15;
    const int lk = (lane >> 4) * 8;

    for (int k0 = 0; k0 < K; k0 += 32) {
        __syncthreads();
        async_cp16(A + (size_t)(m0 + srow)      * K + k0 + scol, As + w * 512);
        async_cp16(A + (size_t)(m0 + srow + 64) * K + k0 + scol, As + 2048 + w * 512);
        async_cp16(B + (size_t)(n0 + srow)      * K + k0 + scol, Bs + w * 512);
        async_cp16(B + (size_t)(n0 + srow + 64) * K + k0 + scol, Bs + 2048 + w * 512);
        __syncthreads();

        bf16x8 fa[4], fb[4];
#pragma unroll
        for (int mi = 0; mi < 4; ++mi)
            fa[mi] = *reinterpret_cast<const bf16x8*>(&As[(wr + mi * 16 + lr) * 32 + lk]);
#pragma unroll
        for (int ni = 0; ni < 4; ++ni)
            fb[ni] = *reinterpret_cast<const bf16x8*>(&Bs[(wc + ni * 16 + lr) * 32 + lk]);
#pragma unroll
        for (int mi = 0; mi < 4; ++mi)
#pragma unroll
            for (int ni = 0; ni < 4; ++ni)
                acc[mi][ni] = __builtin_amdgcn_mfma_f32_16x16x32_bf16(
                    fa[mi], fb[ni], acc[mi][ni], 0, 0, 0);
    }

    const int rbase = (lane >> 4) * 4;
#pragma unroll
    for (int mi = 0; mi < 4; ++mi)
#pragma unroll
        for (int ni = 0; ni < 4; ++ni) {
            const int col = n0 + wc + ni * 16 + lr;
#pragma unroll
            for (int j = 0; j < 4; ++j) {
                const int row = m0 + wr + mi * 16 + rbase + j;
                C[(size_t)row * N + col] = f2bf(acc[mi][ni][j]);
            }
        }
}

// ---------------------------------------------------------------------------
// Generalized pair recurrence coefficients (j=0 packs DC + Nyquist reals).
// ---------------------------------------------------------------------------
__device__ __forceinline__ void pair_coef(const float* lam, int j,
                                          float& lr, float& lr2, float& cr) {
    const float a = lam[2 * j];
    const float b = lam[2 * j + 1];
    if (j == 0) { lr = a; lr2 = b; cr = 0.0f; }
    else        { lr = a; lr2 = a; cr = b; }
}

// ---------------------------------------------------------------------------
// 256x256 8-wave bf16 MFMA GEMM — m201-style 8-phase schedule (round-8 proven;
// epilogue switched by SCANEPI). Byte-identical to round 10/12.
// ---------------------------------------------------------------------------
template <int MH, int NH>
__device__ __forceinline__ void quad_mfma(f32x4 (&acc)[2][2][4][2],
                                          const bf16x8 (&fa)[4][2],
                                          const bf16x8 (&fb)[2][2]) {
#pragma unroll
    for (int mi = 0; mi < 4; ++mi)
#pragma unroll
        for (int ni = 0; ni < 2; ++ni) {
            acc[MH][NH][mi][ni] = __builtin_amdgcn_mfma_f32_16x16x32_bf16(
                fa[mi][0], fb[ni][0], acc[MH][NH][mi][ni], 0, 0, 0);
            acc[MH][NH][mi][ni] = __builtin_amdgcn_mfma_f32_16x16x32_bf16(
                fa[mi][1], fb[ni][1], acc[MH][NH][mi][ni], 0, 0, 0);
        }
}

__device__ __forceinline__ void ld_fa(bf16x8 (&fa)[4][2], const ushort_t* hb,
                                      int wm, int lr, int c0, int c1) {
#pragma unroll
    for (int mi = 0; mi < 4; ++mi) {
        const ushort_t* p = hb + (wm * 64 + mi * 16 + lr) * 64;
        fa[mi][0] = *reinterpret_cast<const bf16x8*>(p + c0);
        fa[mi][1] = *reinterpret_cast<const bf16x8*>(p + c1);
    }
}
__device__ __forceinline__ void ld_fb(bf16x8 (&fb)[2][2], const ushort_t* hb,
                                      int wn, int lr, int c0, int c1) {
#pragma unroll
    for (int ni = 0; ni < 2; ++ni) {
        const ushort_t* p = hb + (wn * 32 + ni * 16 + lr) * 64;
        fb[ni][0] = *reinterpret_cast<const bf16x8*>(p + c0);
        fb[ni][1] = *reinterpret_cast<const bf16x8*>(p + c1);
    }
}

#define HS_STRIDE 260

template <bool SCANEPI>
__global__ __launch_bounds__(512, 2) void gemm256(const ushort_t* __restrict__ A,
                                                  const ushort_t* __restrict__ B,
                                                  void* __restrict__ Cv,
                                                  int M, int K,
                                                  const float* __restrict__ uu,
                                                  const float* __restrict__ Dv,
                                                  const int* __restrict__ dflag,
                                                  const float* __restrict__ lam,
                                                  float2* __restrict__ G) {
    __shared__ ushort_t smem[66560];   // As/Bs (65536) aliased with Hs
    const int tid  = threadIdx.x;
    const int lane = tid & 63;
    const int w    = tid >> 6;      // 0..7
    const int wm   = w >> 2;        // 0..1
    const int wn   = w & 3;         // 0..3
    const int m0 = blockIdx.x * 256;
    const int n0 = blockIdx.y * 256;
    const int lr = lane & 15;
    const int lk = (lane >> 4) * 8;
    const int xv = (lr & 7) << 3;
    const int c0 = lk ^ xv;
    const int c1 = (32 + lk) ^ xv;

    const int rA = tid >> 3;
    const int cS = ((tid & 7) << 3) ^ ((rA & 7) << 3);
    const int ldsOff = w << 9;

    auto ApH = [&](int buf, int half) { return smem + (buf * 2 + half) * 8192; };
    auto BpH = [&](int buf, int half) { return smem + 32768 + (buf * 2 + half) * 8192; };

    f32x4 acc[2][2][4][2] = {};
    bf16x8 fa[4][2], fbl[2][2], fbh[2][2];

    auto stA = [&](int buf, int half, int k) {
#pragma unroll
        for (int li = 0; li < 2; ++li)
            async_cp16(A + (size_t)(m0 + half * 128 + li * 64 + rA) * K + k + cS,
                       ApH(buf, half) + li * 4096 + ldsOff);
    };
    auto stB = [&](int buf, int half, int k) {
#pragma unroll
        for (int li = 0; li < 2; ++li)
            async_cp16(B + (size_t)(n0 + half * 128 + li * 64 + rA) * K + k + cS,
                       BpH(buf, half) + li * 4096 + ldsOff);
    };

    stA(0, 0, 0); stB(0, 0, 0); stB(0, 1, 0); stA(0, 1, 0);
    stA(1, 0, 64); stB(1, 0, 64); stB(1, 1, 64);
    VM6();
    BAR();

    const int niter = K >> 7;
#pragma unroll 1
    for (int t = 0; t < niter - 1; ++t) {
        const int kb1 = (t << 7) + 64;
        const int kn  = (t + 1) << 7;
        const int kn2 = kn + 64;
        // P1
        ld_fa(fa, ApH(0, 0), wm, lr, c0, c1);
        ld_fb(fbl, BpH(0, 0), wn, lr, c0, c1);
        stA(1, 1, kb1);
        LGKM8();
        BAR(); LGKM0();
        PRIO1(); quad_mfma<0, 0>(acc, fa, fbl); PRIO0();
        BAR();
        // P2
        ld_fb(fbh, BpH(0, 1), wn, lr, c0, c1);
        stA(0, 0, kn);
        BAR(); LGKM0();
        PRIO1(); quad_mfma<0, 1>(acc, fa, fbh); PRIO0();
        BAR();
        // P3
        ld_fa(fa, ApH(0, 1), wm, lr, c0, c1);
        stB(0, 0, kn);
        BAR(); LGKM0();
        PRIO1(); quad_mfma<1, 1>(acc, fa, fbh); PRIO0();
        BAR();
        // P4
        stB(0, 1, kn);
        VM6();
        BAR();
        PRIO1(); quad_mfma<1, 0>(acc, fa, fbl); PRIO0();
        BAR();
        // P5
        ld_fa(fa, ApH(1, 0), wm, lr, c0, c1);
        ld_fb(fbl, BpH(1, 0), wn, lr, c0, c1);
        stA(0, 1, kn);
        LGKM8();
        BAR(); LGKM0();
        PRIO1(); quad_mfma<0, 0>(acc, fa, fbl); PRIO0();
        BAR();
        // P6
        ld_fb(fbh, BpH(1, 1), wn, lr, c0, c1);
        stA(1, 0, kn2);
        BAR(); LGKM0();
        PRIO1(); quad_mfma<0, 1>(acc, fa, fbh); PRIO0();
        BAR();
        // P7
        ld_fa(fa, ApH(1, 1), wm, lr, c0, c1);
        stB(1, 0, kn2);
        BAR(); LGKM0();
        PRIO1(); quad_mfma<1, 1>(acc, fa, fbh); PRIO0();
        BAR();
        // P8
        stB(1, 1, kn2);
        VM6();
        BAR();
        PRIO1(); quad_mfma<1, 0>(acc, fa, fbl); PRIO0();
        BAR();
    }
    // epilogue iteration
    {
        const int kb1 = ((niter - 1) << 7) + 64;
        ld_fa(fa, ApH(0, 0), wm, lr, c0, c1);
        ld_fb(fbl, BpH(0, 0), wn, lr, c0, c1);
        stA(1, 1, kb1);
        LGKM8();
        BAR(); LGKM0();
        PRIO1(); quad_mfma<0, 0>(acc, fa, fbl); PRIO0();
        BAR();
        ld_fb(fbh, BpH(0, 1), wn, lr, c0, c1);
        BAR(); LGKM0();
        PRIO1(); quad_mfma<0, 1>(acc, fa, fbh); PRIO0();
        BAR();
        ld_fa(fa, ApH(0, 1), wm, lr, c0, c1);
        BAR(); LGKM0();
        PRIO1(); quad_mfma<1, 1>(acc, fa, fbh); PRIO0();
        BAR();
        VM0();
        BAR();
        PRIO1(); quad_mfma<1, 0>(acc, fa, fbl); PRIO0();
        BAR();
        ld_fa(fa, ApH(1, 0), wm, lr, c0, c1);
        ld_fb(fbl, BpH(1, 0), wn, lr, c0, c1);
        BAR(); LGKM0();
        PRIO1(); quad_mfma<0, 0>(acc, fa, fbl); PRIO0();
        BAR();
        ld_fb(fbh, BpH(1, 1), wn, lr, c0, c1);
        BAR(); LGKM0();
        PRIO1(); quad_mfma<0, 1>(acc, fa, fbh); PRIO0();
        BAR();
        ld_fa(fa, ApH(1, 1), wm, lr, c0, c1);
        BAR(); LGKM0();
        PRIO1(); quad_mfma<1, 1>(acc, fa, fbh); PRIO0();
        BAR();
        PRIO1(); quad_mfma<1, 0>(acc, fa, fbl); PRIO0();
    }

    const int rbase = (lane >> 4) * 4;
    if (SCANEPI) {
        // ---- fused local scan ----
        BAR();
#pragma unroll
        for (int mh = 0; mh < 2; ++mh)
#pragma unroll
            for (int nh = 0; nh < 2; ++nh)
#pragma unroll
                for (int mi = 0; mi < 4; ++mi)
#pragma unroll
                    for (int ni = 0; ni < 2; ++ni) {
                        const int cl = nh * 128 + wn * 32 + ni * 16 + lr;
#pragma unroll
                        for (int j = 0; j < 4; ++j) {
                            const int rl = mh * 128 + wm * 64 + mi * 16 + rbase + j;
                            smem[rl * HS_STRIDE + cl] = f2bf(acc[mh][nh][mi][ni][j]);
                        }
                    }
        BAR();
        const int chunk = tid >> 7;
        const int p = tid & 127;
        const int jg = (n0 >> 1) + p;
        float lr_, lr2_, cr_;
        pair_coef(lam, jg, lr_, lr2_, cr_);
        uint_t* gout = reinterpret_cast<uint_t*>((ushort_t*)Cv +
                        (size_t)(m0 + chunk * TC) * NSPEC) + jg;
        float er = 0.0f, ei = 0.0f;
        for (int t = 0; t < TC; ++t) {
            const uint_t v = *reinterpret_cast<const uint_t*>(
                &smem[(chunk * TC + t) * HS_STRIDE + 2 * p]);
            const float ur = bf2f((ushort_t)(v & 0xFFFF));
            const float ui = bf2f((ushort_t)(v >> 16));
            const float nr = fmaf(lr_, er, fmaf(-cr_, ei, ur));
            const float ni = fmaf(lr2_, ei, fmaf(cr_, er, ui));
            gout[(size_t)t * NPAIR] = (uint_t)f2bf(nr) | ((uint_t)f2bf(ni) << 16);
            er = nr; ei = ni;
        }
        const int b = m0 >> 11;
        const int cg = ((m0 & 2047) >> 6) + chunk;
        G[(size_t)(b * NC + cg) * NPAIR + jg] = make_float2(er, ei);
    } else {
        float* C = (float*)Cv;
        const bool du = (*dflag != 0);
#pragma unroll
        for (int mh = 0; mh < 2; ++mh)
#pragma unroll
            for (int nh = 0; nh < 2; ++nh)
#pragma unroll
                for (int mi = 0; mi < 4; ++mi)
#pragma unroll
                    for (int ni = 0; ni < 2; ++ni) {
                        const int col = n0 + nh * 128 + wn * 32 + ni * 16 + lr;
#pragma unroll
                        for (int j = 0; j < 4; ++j) {
                            const int row = m0 + mh * 128 + wm * 64 + mi * 16 + rbase + j;
                            float v = acc[mh][nh][mi][ni][j];
                            if (du) v = fmaf(Dv[col], uu[(size_t)row * DMODEL + col], v);
                            C[(size_t)row * DMODEL + col] = v;
                        }
                    }
    }
}

// ---------------------------------------------------------------------------
// carry (inline, from G) + broadcast: H[t] += Λ^{t+1}·E_c  (in place, bf16)
// grid covers c = 1..31 only; c is uniform per block.
// ---------------------------------------------------------------------------
__global__ __launch_bounds__(256) void scan_applyc(ushort_t* __restrict__ UHb,
                                                   const float* __restrict__ lam,
                                                   const float2* __restrict__ G) {
    const int gid = blockIdx.x * 256 + threadIdx.x;   // BATCH*31*NPAIR
    const int j = gid & (NPAIR - 1);
    const int s9 = gid >> 9;
    const int c = 1 + s9 % 31;
    const int b = s9 / 31;
    float lr, lr2, cr;
    pair_coef(lam, j, lr, lr2, cr);
    // P = Λ^64 via 6 closed-form squarings
    float pr = lr, pr2 = lr2, pc = cr;
    for (int s = 0; s < 6; ++s) {
        const float nr  = pr * pr - pc * pc;
        const float nr2 = pr2 * pr2 - pc * pc;
        const float npc = pc * (pr + pr2);
        pr = nr; pr2 = nr2; pc = npc;
    }
    // carry into chunk c: E = P·E + G[c'] over c' = 0..c-1  (G is L2-resident)
    float er = 0.0f, ei = 0.0f;
    for (int cp = 0; cp < c; ++cp) {
        const float2 g = G[(size_t)(b * NC + cp) * NPAIR + j];
        const float nr = fmaf(pr, er, fmaf(-pc, ei, g.x));
        const float ni = fmaf(pr2, ei, fmaf(pc, er, g.y));
        er = nr; ei = ni;
    }
    // s = Λ^{t+1}·E, iterated
    float sr = fmaf(lr, er, -cr * ei);
    float si = fmaf(lr2, ei, cr * er);
    uint_t* base = reinterpret_cast<uint_t*>(
        UHb + (size_t)(b * SEQLEN + c * TC) * NSPEC) + j;
    for (int t = 0; t < TC; ++t) {
        const uint_t v = base[(size_t)t * NPAIR];
        const float hr = bf2f((ushort_t)(v & 0xFFFF)) + sr;
        const float hi = bf2f((ushort_t)(v >> 16)) + si;
        base[(size_t)t * NPAIR] = (uint_t)f2bf(hr) | ((uint_t)f2bf(hi) << 16);
        const float nsr = fmaf(lr, sr, -cr * si);
        const float nsi = fmaf(lr2, si, cr * sr);
        sr = nsr; si = nsi;
    }
}

// ---------------------------------------------------------------------------
extern "C" void kernel_launch(void* const* d_in, const int* in_sizes, int n_in,
                              void* d_out, int out_size, void* d_ws, size_t ws_size,
                              hipStream_t stream) {
    const float* u  = (const float*)d_in[0];  // [B][S][D]
    const float* ap = (const float*)d_in[1];  // [512]
    const float* Bw = (const float*)d_in[2];  // [N][D]
    const float* Cw = (const float*)d_in[3];  // [D][N]
    const float* Dv = (const float*)d_in[4];  // [D]
    float* out = (float*)d_out;               // [B][S][D]

    char* ws = (char*)d_ws;
    size_t off = 0;
    auto carve = [&](size_t bytes) { char* p = ws + off; off += (bytes + 255) & ~(size_t)255; return p; };

    ushort_t* UHb  = (ushort_t*)carve((size_t)BT_ROWS * NSPEC * sizeof(ushort_t));  // 33.6 MB
    ushort_t* ub   = (ushort_t*)carve((size_t)BT_ROWS * DMODEL * sizeof(ushort_t)); // 33.6 MB
    ushort_t* T1b  = (ushort_t*)carve((size_t)NSPEC * DMODEL * sizeof(ushort_t));
    ushort_t* T2b  = (ushort_t*)carve((size_t)NSPEC * DMODEL * sizeof(ushort_t));
    ushort_t* BwTb = (ushort_t*)carve((size_t)DMODEL * DMODEL * sizeof(ushort_t));
    ushort_t* Cwb  = (ushort_t*)carve((size_t)DMODEL * DMODEL * sizeof(ushort_t));
    ushort_t* W1b  = (ushort_t*)carve((size_t)NSPEC * DMODEL * sizeof(ushort_t));
    ushort_t* W2b  = (ushort_t*)carve((size_t)DMODEL * NSPEC * sizeof(ushort_t));
    float*    lam  = (float*)   carve(NSPEC * sizeof(float));
    int*      dflag= (int*)     carve(sizeof(int));
    float2*   G    = (float2*)  carve((size_t)BATCH * NC * NPAIR * sizeof(float2));

    // 1) lambda + dflag + trig matrices + Bw transpose + Cw/u conversions
    prep_all<<<1 + 2 * NB_T + NB_TR + NB_CW + NB_U, 256, 0, stream>>>(
        ap, lam, Dv, dflag, Cw, Cwb, Bw, BwTb, T1b, T2b, u, ub);

    // 2) both weight GEMMs (standalone; operands L2-resident)
    {
        dim3 g(8, 8, 2);
        gemm128z<<<g, 256, 0, stream>>>(T1b, BwTb, W1b, Cwb, T2b, W2b);
    }

    // 3) GEMM-U + fused local scan
    {
        dim3 g(BT_ROWS / 256, NSPEC / 256);
        gemm256<true><<<g, 512, 0, stream>>>(ub, W1b, UHb,
            BT_ROWS, DMODEL, nullptr, nullptr, dflag, lam, G);
    }

    // 4) inline carry + broadcast (c = 1..31)
    scan_applyc<<<BATCH * 31 * NPAIR / 256, 256, 0, stream>>>(UHb, lam, G);

    // 5) y = UHb @ W2b^T + D*u
    {
        dim3 g(BT_ROWS / 256, DMODEL / 256);
        gemm256<false><<<g, 512, 0, stream>>>(UHb, W2b, out,
            BT_ROWS, NSPEC, u, Dv, dflag, lam, nullptr);
    }
}